// Round 3
// baseline (556.875 us; speedup 1.0000x reference)
//
#include <hip/hip_runtime.h>
#include <hip/hip_fp16.h>

#define NN 50000
#define NE 800000
#define D 128
#define NB 196        // ceil(50000/256)
#define FILL_BLOCKS 1024
#define GEMM_BLOCKS 3128   // 782 * 4
#define RNG 6250      // NN / 8 (dst range per XCD)
#define ESL 6250      // NE / 128 (edge slice per fill-rank)

typedef _Float16 half8_t __attribute__((ext_vector_type(8)));
typedef _Float16 half4_t __attribute__((ext_vector_type(4)));
typedef float f32x4 __attribute__((ext_vector_type(4)));

// ---------------- K0: init counters + summary slots + W transpose to half ----------------
// WT[n][k] = (half)W[k][n] precomputed ONCE here; GEMM waves then load w-fragments
// directly from global (L2-resident 32KB) instead of re-staging W through LDS per block.
__global__ void k_init(int* cnt1, int* cnt2, float* s1, float* s2,
                       const float* __restrict__ W1, const float* __restrict__ W2,
                       _Float16* wt1, _Float16* wt2) {
    int i = blockIdx.x * blockDim.x + threadIdx.x;
    int stride = gridDim.x * blockDim.x;
    for (int j = i; j < NN; j += stride) { cnt1[j] = 0; cnt2[j] = 0; }
    if (i < D) { s1[i] = 0.f; s2[i] = 0.f; }
    if (i < 16384) {
        int n = i >> 7, k = i & 127;          // write coalesced, read strided (64KB, trivial)
        wt1[n * 128 + k] = (_Float16)W1[k * 128 + n];
        wt2[n * 128 + k] = (_Float16)W2[k * 128 + n];
    }
}

// ---------------- K1: in-degree histogram, XCD-binned ----------------
__global__ void k_count(const int* __restrict__ dst1, const int* __restrict__ dst2,
                        int* cnt1, int* cnt2) {
    int r = blockIdx.x & 7;
    int rank = blockIdx.x >> 3;          // 0..127
    unsigned lo = r * RNG;
    int base = rank * ESL;
    for (int e = base + threadIdx.x; e < base + ESL; e += 256) {
        int d1 = dst1[e];
        if ((unsigned)(d1 - lo) < RNG) atomicAdd(&cnt1[d1], 1);
        int d2 = dst2[e];
        if ((unsigned)(d2 - lo) < RNG) atomicAdd(&cnt2[d2], 1);
    }
}

// ---------------- K2a: per-block partial sums of counts (both graphs) ----------------
__global__ void k_part(const int* __restrict__ cnt1, const int* __restrict__ cnt2,
                       int* part1, int* part2) {
    __shared__ int sm1[256], sm2[256];
    int t = threadIdx.x;
    int idx = blockIdx.x * 256 + t;
    int v1 = (idx < NN) ? cnt1[idx] : 0;
    int v2 = (idx < NN) ? cnt2[idx] : 0;
    sm1[t] = v1; sm2[t] = v2;
    __syncthreads();
    for (int off = 128; off > 0; off >>= 1) {
        if (t < off) { sm1[t] += sm1[t + off]; sm2[t] += sm2[t + off]; }
        __syncthreads();
    }
    if (t == 0) { part1[blockIdx.x] = sm1[0]; part2[blockIdx.x] = sm2[0]; }
}

// ---------------- K2b: exclusive scan of block partials (one block) ----------------
__global__ void k_scanp(int* part1, int* part2) {
    __shared__ int sm1[256], sm2[256];
    int t = threadIdx.x;
    int v1 = (t < NB) ? part1[t] : 0;
    int v2 = (t < NB) ? part2[t] : 0;
    sm1[t] = v1; sm2[t] = v2;
    __syncthreads();
    for (int off = 1; off < 256; off <<= 1) {
        int a1 = (t >= off) ? sm1[t - off] : 0;
        int a2 = (t >= off) ? sm2[t - off] : 0;
        __syncthreads();
        sm1[t] += a1; sm2[t] += a2;
        __syncthreads();
    }
    if (t < NB) { part1[t] = sm1[t] - v1; part2[t] = sm2[t] - v2; }
}

// ---------------- K2c: apply block offsets -> rp, cur, dinv ----------------
__global__ void k_apply(const int* __restrict__ cnt1, const int* __restrict__ cnt2,
                        const int* __restrict__ part1, const int* __restrict__ part2,
                        int* rp1, int* rp2, int* cur1, int* cur2,
                        float* dinv1, float* dinv2) {
    __shared__ int sm1[256], sm2[256];
    int b = blockIdx.x, t = threadIdx.x;
    int idx = b * 256 + t;
    int v1 = (idx < NN) ? cnt1[idx] : 0;
    int v2 = (idx < NN) ? cnt2[idx] : 0;
    sm1[t] = v1; sm2[t] = v2;
    __syncthreads();
    for (int off = 1; off < 256; off <<= 1) {
        int a1 = (t >= off) ? sm1[t - off] : 0;
        int a2 = (t >= off) ? sm2[t - off] : 0;
        __syncthreads();
        sm1[t] += a1; sm2[t] += a2;
        __syncthreads();
    }
    int e1 = sm1[t] - v1 + part1[b];  // exclusive prefix
    int e2 = sm2[t] - v2 + part2[b];
    if (idx < NN) {
        rp1[idx] = e1; cur1[idx] = e1; dinv1[idx] = rsqrtf((float)(v1 + 1));
        rp2[idx] = e2; cur2[idx] = e2; dinv2[idx] = rsqrtf((float)(v2 + 1));
    } else if (idx == NN) {
        rp1[NN] = e1; rp2[NN] = e2;
    }
}

// ---------------- K3: XCD-binned CSR fill (own kernel: keeps cur/col L2-clean) ----------------
// Separate dispatch (not merged with GEMM): R1 showed co-residency with GEMM streams
// thrashes the fill's L2 working set (162->263us regression).
__global__ void k_fill(const int* __restrict__ src1, const int* __restrict__ dst1,
                       const int* __restrict__ src2, const int* __restrict__ dst2,
                       int* cur1, int* cur2, int* col1, int* col2) {
    int r = blockIdx.x & 7;
    int rank = blockIdx.x >> 3;              // 0..127
    unsigned lo = r * RNG;
    int base = rank * ESL;
    for (int e = base + threadIdx.x; e < base + ESL; e += 256) {
        int d1 = dst1[e];
        if ((unsigned)(d1 - lo) < RNG) {
            int p = atomicAdd(&cur1[d1], 1);
            col1[p] = src1[e];
        }
        int d2 = dst2[e];
        if ((unsigned)(d2 - lo) < RNG) {
            int p = atomicAdd(&cur2[d2], 1);
            col2[p] = src2[e];
        }
    }
}

// ---------------- K4: 4 GEMMs, w-fragments direct from global WT (no staging, no barriers) ----------------
// LDS = per-wave output-transpose scratch only (17.4KB -> ~7 blocks/CU vs 4 before).
__launch_bounds__(256)
__global__ void k_gemm(const _Float16* __restrict__ wt1, const _Float16* __restrict__ wt2,
                       const float* __restrict__ x,
                       const float* __restrict__ mp1, const float* __restrict__ mn1,
                       const float* __restrict__ mp2, const float* __restrict__ mn2,
                       const int* __restrict__ perm1, const int* __restrict__ perm2,
                       const float* __restrict__ dinv1, const float* __restrict__ dinv2,
                       _Float16* xwi1, _Float16* xwi2) {
    __shared__ __align__(16) _Float16 ST[4][16][136];   // per-wave private transpose scratch

    int g = blockIdx.x;                    // 0..3127
    int which = g / 782;                   // 0 = pos1, 1 = neg1, 2 = pos2, 3 = neg2
    int bx = g - which * 782;
    const _Float16* wt = (which < 2) ? wt1 : wt2;
    const float* mask = (which == 0) ? mp1 : (which == 1) ? mn1 : (which == 2) ? mp2 : mn2;
    const int* perm = (which == 1) ? perm1 : (which == 3) ? perm2 : nullptr;
    const float* dinv = (which < 2) ? dinv1 : dinv2;
    _Float16* out = ((which < 2) ? xwi1 : xwi2) + ((which & 1) ? 128 : 0);

    int t = threadIdx.x;
    int wave = t >> 6;
    int lane = t & 63;
    int quad = lane >> 4;
    int m = lane & 15;
    int tile = bx * 4 + wave;
    if (tile * 16 >= NN) return;           // no barriers anywhere -> safe early return

    int row = tile * 16 + m;
    int grow = perm ? perm[row] : row;
    const float* xrow = x + (long)grow * D;
    const float* mrow = mask + (long)grow * D;

    half8_t a[4];
    #pragma unroll
    for (int kk = 0; kk < 4; kk++) {
        int k0 = kk * 32 + quad * 8;
        float4 xa = *(const float4*)(xrow + k0);
        float4 xb = *(const float4*)(xrow + k0 + 4);
        float4 ma = *(const float4*)(mrow + k0);
        float4 mb = *(const float4*)(mrow + k0 + 4);
        a[kk][0] = (_Float16)(xa.x * ma.x);
        a[kk][1] = (_Float16)(xa.y * ma.y);
        a[kk][2] = (_Float16)(xa.z * ma.z);
        a[kk][3] = (_Float16)(xa.w * ma.w);
        a[kk][4] = (_Float16)(xb.x * mb.x);
        a[kk][5] = (_Float16)(xb.y * mb.y);
        a[kk][6] = (_Float16)(xb.z * mb.z);
        a[kk][7] = (_Float16)(xb.w * mb.w);
    }

    // Swapped operands: A = W-fragment (out-col), B = x-fragment (x-row).
    // w-fragments straight from global WT[n][k] (L2-resident, 32 independent 16B loads).
    f32x4 accs[8];
    #pragma unroll
    for (int nt = 0; nt < 8; nt++) {
        const _Float16* wrow = wt + (nt * 16 + m) * 128 + quad * 8;
        f32x4 acc = {0.f, 0.f, 0.f, 0.f};
        #pragma unroll
        for (int kk = 0; kk < 4; kk++) {
            half8_t w = *(const half8_t*)(wrow + kk * 32);
            acc = __builtin_amdgcn_mfma_f32_16x16x32_f16(w, a[kk], acc, 0, 0, 0);
        }
        accs[nt] = acc;
    }

    // Per-wave LDS transpose epilogue (wave-private slice -> no __syncthreads needed).
    float ds = dinv[tile * 16 + m];        // one row per lane
    _Float16* st = &ST[wave][0][0];

    #pragma unroll
    for (int nt = 0; nt < 8; nt++) {
        half4_t h;
        h[0] = (_Float16)(accs[nt][0] * ds);
        h[1] = (_Float16)(accs[nt][1] * ds);
        h[2] = (_Float16)(accs[nt][2] * ds);
        h[3] = (_Float16)(accs[nt][3] * ds);
        *(half4_t*)(st + m * 136 + nt * 16 + quad * 4) = h;
    }
    // Read back row-contiguous; every store instr = 16 rows x 64B full aligned lines.
    #pragma unroll
    for (int p = 0; p < 4; p++) {
        int r = lane & 15;
        int cc = (lane >> 4) + p * 4;       // 16B chunk index 0..15
        half8_t v = *(const half8_t*)(st + r * 136 + cc * 8);
        *(half8_t*)(out + (long)(tile * 16 + r) * 256 + cc * 8) = v;
    }
}

// ---------------- K5: CSR gather aggregation + bias + ReLU (no atomics) ----------------
__launch_bounds__(256)
__global__ void k_agg(const _Float16* __restrict__ xwi1, const _Float16* __restrict__ xwi2,
                      const int* __restrict__ rp1, const int* __restrict__ col1,
                      const float* __restrict__ dinv1,
                      const int* __restrict__ rp2, const int* __restrict__ col2,
                      const float* __restrict__ dinv2,
                      const float* __restrict__ b1, const float* __restrict__ b2,
                      float* out) {
    int g = blockIdx.y;
    const _Float16* xwi = g ? xwi2 : xwi1;
    const int* rp = g ? rp2 : rp1;
    const int* col = g ? col2 : col1;
    const float* dinv = g ? dinv2 : dinv1;
    const float* bias = g ? b2 : b1;
    float* pos_out = out + (g ? 12800128L : 0L);
    float* neg_out = out + (g ? 19200128L : 6400000L);

    int t = threadIdx.x;
    int wave = t >> 6, lane = t & 63;
    int i = blockIdx.x * 4 + wave;
    if (i >= NN) return;
    int j4 = lane * 4;

    half4_t sv = *(const half4_t*)(xwi + (long)i * 256 + j4);
    float a0 = (float)sv[0], a1 = (float)sv[1], a2 = (float)sv[2], a3 = (float)sv[3];
    int e0 = rp[i], e1 = rp[i + 1];
    int e = e0;
    for (; e + 8 <= e1; e += 8) {
        int s0 = col[e + 0], s1 = col[e + 1], s2 = col[e + 2], s3 = col[e + 3];
        int s4 = col[e + 4], s5 = col[e + 5], s6 = col[e + 6], s7 = col[e + 7];
        half4_t v0 = *(const half4_t*)(xwi + (long)s0 * 256 + j4);
        half4_t v1 = *(const half4_t*)(xwi + (long)s1 * 256 + j4);
        half4_t v2 = *(const half4_t*)(xwi + (long)s2 * 256 + j4);
        half4_t v3 = *(const half4_t*)(xwi + (long)s3 * 256 + j4);
        half4_t v4 = *(const half4_t*)(xwi + (long)s4 * 256 + j4);
        half4_t v5 = *(const half4_t*)(xwi + (long)s5 * 256 + j4);
        half4_t v6 = *(const half4_t*)(xwi + (long)s6 * 256 + j4);
        half4_t v7 = *(const half4_t*)(xwi + (long)s7 * 256 + j4);
        a0 += (float)v0[0] + (float)v1[0] + (float)v2[0] + (float)v3[0]
            + (float)v4[0] + (float)v5[0] + (float)v6[0] + (float)v7[0];
        a1 += (float)v0[1] + (float)v1[1] + (float)v2[1] + (float)v3[1]
            + (float)v4[1] + (float)v5[1] + (float)v6[1] + (float)v7[1];
        a2 += (float)v0[2] + (float)v1[2] + (float)v2[2] + (float)v3[2]
            + (float)v4[2] + (float)v5[2] + (float)v6[2] + (float)v7[2];
        a3 += (float)v0[3] + (float)v1[3] + (float)v2[3] + (float)v3[3]
            + (float)v4[3] + (float)v5[3] + (float)v6[3] + (float)v7[3];
    }
    for (; e + 4 <= e1; e += 4) {
        int s0 = col[e + 0], s1 = col[e + 1], s2 = col[e + 2], s3 = col[e + 3];
        half4_t v0 = *(const half4_t*)(xwi + (long)s0 * 256 + j4);
        half4_t v1 = *(const half4_t*)(xwi + (long)s1 * 256 + j4);
        half4_t v2 = *(const half4_t*)(xwi + (long)s2 * 256 + j4);
        half4_t v3 = *(const half4_t*)(xwi + (long)s3 * 256 + j4);
        a0 += (float)v0[0] + (float)v1[0] + (float)v2[0] + (float)v3[0];
        a1 += (float)v0[1] + (float)v1[1] + (float)v2[1] + (float)v3[1];
        a2 += (float)v0[2] + (float)v1[2] + (float)v2[2] + (float)v3[2];
        a3 += (float)v0[3] + (float)v1[3] + (float)v2[3] + (float)v3[3];
    }
    for (; e < e1; e++) {
        int s = col[e];
        half4_t v = *(const half4_t*)(xwi + (long)s * 256 + j4);
        a0 += (float)v[0]; a1 += (float)v[1]; a2 += (float)v[2]; a3 += (float)v[3];
    }
    float di = dinv[i];
    int jj = (lane < 32) ? j4 : (j4 - 128);
    const f32x4* bp = (const f32x4*)(bias + jj);
    f32x4 bv = *bp;
    f32x4 o;
    o[0] = fmaxf(0.f, di * a0 + bv[0]);
    o[1] = fmaxf(0.f, di * a1 + bv[1]);
    o[2] = fmaxf(0.f, di * a2 + bv[2]);
    o[3] = fmaxf(0.f, di * a3 + bv[3]);
    float* dst = ((lane < 32) ? pos_out : neg_out) + (long)i * D + jj;
    __builtin_nontemporal_store(o, (f32x4*)dst);
}

// ---------------- K6: summary mean over pos_h ----------------
__launch_bounds__(256)
__global__ void k_sum(const float* __restrict__ pos1, const float* __restrict__ pos2,
                      float* s1, float* s2) {
    int g = blockIdx.y;
    const float* pos = g ? pos2 : pos1;
    float* s = g ? s2 : s1;
    int t = threadIdx.x;
    int rg = t >> 5;
    int j = (t & 31) * 4;
    float4 acc = {0.f, 0.f, 0.f, 0.f};
    for (int i = blockIdx.x * 8 + rg; i < NN; i += gridDim.x * 8) {
        float4 v = *(const float4*)(pos + (long)i * D + j);
        acc.x += v.x; acc.y += v.y; acc.z += v.z; acc.w += v.w;
    }
    __shared__ float sm[8][128];
    sm[rg][j + 0] = acc.x;
    sm[rg][j + 1] = acc.y;
    sm[rg][j + 2] = acc.z;
    sm[rg][j + 3] = acc.w;
    __syncthreads();
    if (t < 128) {
        float v = 0.f;
        for (int r = 0; r < 8; r++) v += sm[r][t];
        atomicAdd(&s[t], v * (1.0f / NN));
    }
}

extern "C" void kernel_launch(void* const* d_in, const int* in_sizes, int n_in,
                              void* d_out, int out_size, void* d_ws, size_t ws_size,
                              hipStream_t stream) {
    const float* x   = (const float*)d_in[0];
    const float* W1  = (const float*)d_in[1];
    const float* b1  = (const float*)d_in[2];
    const float* W2  = (const float*)d_in[3];
    const float* b2  = (const float*)d_in[4];
    const float* mp1 = (const float*)d_in[5];
    const float* mn1 = (const float*)d_in[6];
    const float* mp2 = (const float*)d_in[7];
    const float* mn2 = (const float*)d_in[8];
    const int* e1 = (const int*)d_in[9];
    const int* e2 = (const int*)d_in[10];
    const int* perm1 = (const int*)d_in[11];
    const int* perm2 = (const int*)d_in[12];
    const int* src1 = e1;       const int* dst1 = e1 + NE;
    const int* src2 = e2;       const int* dst2 = e2 + NE;
    float* out = (float*)d_out;

    // workspace carve
    char* w = (char*)d_ws;
    _Float16* xwi1 = (_Float16*)w; w += (size_t)NN * 256 * 2;  // 25.6 MB interleaved
    _Float16* xwi2 = (_Float16*)w; w += (size_t)NN * 256 * 2;
    int* cnt1 = (int*)w;  w += (size_t)NN * 4;
    int* cnt2 = (int*)w;  w += (size_t)NN * 4;
    int* cur1 = (int*)w;  w += (size_t)NN * 4;
    int* cur2 = (int*)w;  w += (size_t)NN * 4;
    int* rp1 = (int*)w;   w += (size_t)(NN + 4) * 4;
    int* rp2 = (int*)w;   w += (size_t)(NN + 4) * 4;
    int* col1 = (int*)w;  w += (size_t)NE * 4;
    int* col2 = (int*)w;  w += (size_t)NE * 4;
    float* dinv1 = (float*)w; w += (size_t)NN * 4;
    float* dinv2 = (float*)w; w += (size_t)NN * 4;
    int* part1 = (int*)w; w += (size_t)256 * 4;
    int* part2 = (int*)w; w += (size_t)256 * 4;
    _Float16* wt1 = (_Float16*)w; w += (size_t)D * D * 2;   // 32 KB transposed half W1
    _Float16* wt2 = (_Float16*)w; w += (size_t)D * D * 2;

    float* s1 = out + 12800000L;
    float* s2 = out + 25600128L;
    const float* pos1 = out;
    const float* pos2 = out + 12800128L;

    k_init<<<dim3(256), 256, 0, stream>>>(cnt1, cnt2, s1, s2, W1, W2, wt1, wt2);
    k_count<<<dim3(1024), 256, 0, stream>>>(dst1, dst2, cnt1, cnt2);
    k_part<<<dim3(NB), 256, 0, stream>>>(cnt1, cnt2, part1, part2);
    k_scanp<<<dim3(1), 256, 0, stream>>>(part1, part2);
    k_apply<<<dim3(NB), 256, 0, stream>>>(cnt1, cnt2, part1, part2,
                                          rp1, rp2, cur1, cur2, dinv1, dinv2);
    k_fill<<<dim3(FILL_BLOCKS), 256, 0, stream>>>(src1, dst1, src2, dst2,
                                                  cur1, cur2, col1, col2);
    k_gemm<<<dim3(GEMM_BLOCKS), 256, 0, stream>>>(wt1, wt2,
        x, mp1, mn1, mp2, mn2, perm1, perm2, dinv1, dinv2, xwi1, xwi2);
    k_agg<<<dim3(12500, 2), 256, 0, stream>>>(xwi1, xwi2,
                                              rp1, col1, dinv1, rp2, col2, dinv2,
                                              b1, b2, out);
    k_sum<<<dim3(128, 2), 256, 0, stream>>>(pos1, pos2, s1, s2);
}